// Round 2
// 332.180 us; speedup vs baseline: 1.3526x; 1.3526x over previous
//
#include <hip/hip_runtime.h>
#include <hip/hip_bf16.h>

#define B_ 64
#define N_ 2048
#define I_ 16
#define J_ 32
#define O_ 32
#define JO_ 1024

typedef __attribute__((ext_vector_type(8))) short bf16x8;
typedef __attribute__((ext_vector_type(16))) float f32x16;
typedef unsigned short u16;
typedef unsigned int u32;

__device__ __forceinline__ float bf2f(u16 u) {
  union { u32 i; float f; } c; c.i = ((u32)u) << 16; return c.f;
}
__device__ __forceinline__ u16 f2bf(float f) {
  union { float f; u32 i; } c; c.f = f;
  u32 r = (c.i + 0x7fffu + ((c.i >> 16) & 1u)) >> 16;
  return (u16)r;
}
__device__ __forceinline__ u32 pack2(float a, float b) {
  return (u32)f2bf(a) | ((u32)f2bf(b) << 16);
}
__device__ __forceinline__ u32 scale2(u32 p, float cv) {
  return pack2(bf2f((u16)(p & 0xffffu)) * cv, bf2f((u16)(p >> 16)) * cv);
}

// ---------------------------------------------------------------------------
// xconv: x f32 [b][n][i] -> xt bf16 [n][b][i]
// ---------------------------------------------------------------------------
__global__ __launch_bounds__(256) void xconv_kernel(
    const float* __restrict__ xf, u16* __restrict__ xt)
{
  const int idx = blockIdx.x * 256 + threadIdx.x;   // = b*2048 + n
  const int b = idx >> 11, n = idx & 2047;
  const float4* sp = (const float4*)(xf + (size_t)idx * 16);
  float4 f0 = sp[0], f1 = sp[1], f2 = sp[2], f3 = sp[3];
  uint4 d0, d1;
  d0.x = pack2(f0.x, f0.y); d0.y = pack2(f0.z, f0.w);
  d0.z = pack2(f1.x, f1.y); d0.w = pack2(f1.z, f1.w);
  d1.x = pack2(f2.x, f2.y); d1.y = pack2(f2.z, f2.w);
  d1.z = pack2(f3.x, f3.y); d1.w = pack2(f3.z, f3.w);
  uint4* dp = (uint4*)(xt + ((size_t)n * 64 + b) * 16);
  dp[0] = d0; dp[1] = d1;
}

// ---------------------------------------------------------------------------
// wconv: w f32 [n][jo][i] -> wb bf16 (same layout). 2M rows of 16.
// ---------------------------------------------------------------------------
__global__ __launch_bounds__(256) void wconv_kernel(
    const float* __restrict__ wf, u16* __restrict__ wb)
{
  const size_t row = (size_t)blockIdx.x * 256 + threadIdx.x;
  const float4* sp = (const float4*)(wf + row * 16);
  float4 f0 = sp[0], f1 = sp[1], f2 = sp[2], f3 = sp[3];
  uint4 d0, d1;
  d0.x = pack2(f0.x, f0.y); d0.y = pack2(f0.z, f0.w);
  d0.z = pack2(f1.x, f1.y); d0.w = pack2(f1.z, f1.w);
  d1.x = pack2(f2.x, f2.y); d1.y = pack2(f2.z, f2.w);
  d1.z = pack2(f3.x, f3.y); d1.w = pack2(f3.z, f3.w);
  uint4* dp = (uint4*)(wb + row * 16);
  dp[0] = d0; dp[1] = d1;
}

// ---------------------------------------------------------------------------
// SF kernel: s_sum[jo][b] += sum_n c[b,n,j] * pred[b,n,jo]
// MFMA 32x32x16: A = w[n] rows (M=32 = one j-tile), B = x cols b, K=16=I.
// Dual-half: both b-halves per wave, sharing the A fragment (wb read once).
// splits=32 (NPW=16): grid (32 j, 32 split) = 1024 blocks -> 16 waves/CU
// (was 512 blocks = 25% occupancy cap; kernel is latency-bound).
// ---------------------------------------------------------------------------
#define SF_NPW 16

__global__ __launch_bounds__(256, 4) void sf_kernel(
    const u16* __restrict__ xt, const u16* __restrict__ wb,
    const u16* __restrict__ ct, float* __restrict__ s_sum, int uniform)
{
  __shared__ float red[4][2048];   // 32 KB
  const int tid = threadIdx.x;
  const int wave = tid >> 6, lane = tid & 63;
  const int l31 = lane & 31, h = lane >> 5;
  const int j = blockIdx.x, split = blockIdx.y;
  const int n0 = (split * 4 + wave) * SF_NPW;
  f32x16 acc0 = {0.f, 0.f, 0.f, 0.f, 0.f, 0.f, 0.f, 0.f,
                 0.f, 0.f, 0.f, 0.f, 0.f, 0.f, 0.f, 0.f};
  f32x16 acc1 = acc0;

  #pragma unroll 4
  for (int i = 0; i < SF_NPW; ++i) {
    const int n = n0 + i;
    // A-frag: w[n][j*32 + l31][i = h*8..+8]
    bf16x8 wfr = *(const bf16x8*)(wb + ((size_t)n * JO_ + j * 32 + l31) * 16 + h * 8);
    // B-frags: x cols b = l31 and 32+l31
    bf16x8 x0 = *(const bf16x8*)(xt + ((size_t)n * 64 + l31) * 16 + h * 8);
    bf16x8 x1 = *(const bf16x8*)(xt + ((size_t)n * 64 + 32 + l31) * 16 + h * 8);
    if (!uniform) {
      const float cv0 = bf2f(ct[((size_t)j * N_ + n) * 64 + l31]);
      const float cv1 = bf2f(ct[((size_t)j * N_ + n) * 64 + 32 + l31]);
      union { bf16x8 v; u32 u[4]; } a, b2;
      a.v = x0; b2.v = x1;
      a.u[0] = scale2(a.u[0], cv0); a.u[1] = scale2(a.u[1], cv0);
      a.u[2] = scale2(a.u[2], cv0); a.u[3] = scale2(a.u[3], cv0);
      b2.u[0] = scale2(b2.u[0], cv1); b2.u[1] = scale2(b2.u[1], cv1);
      b2.u[2] = scale2(b2.u[2], cv1); b2.u[3] = scale2(b2.u[3], cv1);
      x0 = a.v; x1 = b2.v;
    }
    acc0 = __builtin_amdgcn_mfma_f32_32x32x16_bf16(wfr, x0, acc0, 0, 0, 0);
    acc1 = __builtin_amdgcn_mfma_f32_32x32x16_bf16(wfr, x1, acc1, 0, 0, 0);
  }
  // C layout: col=lane&31 (=b), row o = (r&3)+8*(r>>2)+4h
  #pragma unroll
  for (int r = 0; r < 16; ++r) {
    const int o = (r & 3) + 8 * (r >> 2) + 4 * h;
    red[wave][o * 64 + l31] = acc0[r];
    red[wave][o * 64 + 32 + l31] = acc1[r];
  }
  __syncthreads();
  #pragma unroll
  for (int k = 0; k < 8; ++k) {
    const int idx = tid + 256 * k;
    const int o = idx >> 6, b = idx & 63;
    const float sum = red[0][idx] + red[1][idx] + red[2][idx] + red[3][idx];
    atomicAdd(&s_sum[(size_t)(j * 32 + o) * 64 + b], sum);
  }
}

// ---------------------------------------------------------------------------
// R kernel: squash over o from s_sum[jo][b].
// mode 0: write v f32 + v4=f2bf(v); 1: v4=f2bf(v+vprev); 2: write out.
// v4 layout [j][g][h][b][4o] (ushort4 per (j,g,h,b)) so a_kernel's dot loads
// are contiguous per half-wave instead of a 64-line gather.
// grid 1024 (= 64 b x 16 jgroups), block 64 (2 j x 32 o).
// ---------------------------------------------------------------------------
__global__ __launch_bounds__(64) void r_kernel(
    const float* __restrict__ s_sum, float* __restrict__ v,
    const float* __restrict__ vprev, u16* __restrict__ v4,
    float* __restrict__ out, int mode, float scale)
{
  const int tid = threadIdx.x;
  const int jj = tid >> 5, o = tid & 31;
  const int b = blockIdx.x >> 4, jg = blockIdx.x & 15;
  const int j = jg * 2 + jj;
  const float s = s_sum[(size_t)(j * 32 + o) * 64 + b] * scale;
  float sq = s * s;
  #pragma unroll
  for (int m = 16; m >= 1; m >>= 1) sq += __shfl_xor(sq, m, 64);
  const float sc = sq / (1.f + sq) * rsqrtf(sq + 1e-8f);
  const float vv = sc * s;
  const size_t off = (size_t)b * JO_ + j * 32 + o;
  const int g = o >> 3, hh = (o >> 2) & 1, rr = o & 3;
  const size_t v4off = ((((size_t)j * 4 + g) * 2 + hh) * 64 + b) * 4 + rr;
  if (mode == 0) { v[off] = vv; v4[v4off] = f2bf(vv); }
  else if (mode == 1) { v4[v4off] = f2bf(vv + vprev[off]); }
  else { out[off] = vv; }
}

// ---------------------------------------------------------------------------
// A kernel: 4 waves = 2 n x 2 t-halves (16 j-tiles per wave).
// Logits go STRAIGHT to LDS (old version's lg0[32]/lg1[32] with runtime index
// spilled to scratch: 67 MB of hidden traffic, the measured WRITE_SIZE bloat).
// v read via v4[j][g][h][b][4] -> contiguous 256B per half-wave per load.
// Softmax phase: 128 threads, one (n,b) each, in-register over 32 j.
// grid 1024, block 256 -> 4096 waves = 50% occupancy (was 25% cap).
// ---------------------------------------------------------------------------
__global__ __launch_bounds__(256, 4) void a_kernel(
    const u16* __restrict__ xt, const u16* __restrict__ wb,
    const u16* __restrict__ v4, u16* __restrict__ ct)
{
  __shared__ float lgs[2][64][33];   // [nl][b][j], pad 33 -> conflict-free
  const int tid = threadIdx.x;
  const int wave = tid >> 6, lane = tid & 63;
  const int l31 = lane & 31, h = lane >> 5;
  const int nl = wave >> 1, th = wave & 1;
  const int n = blockIdx.x * 2 + nl;
  const f32x16 zero16 = {0.f, 0.f, 0.f, 0.f, 0.f, 0.f, 0.f, 0.f,
                         0.f, 0.f, 0.f, 0.f, 0.f, 0.f, 0.f, 0.f};

  // B-frags: x cols b = l31 and 32+l31
  const bf16x8 x0 = *(const bf16x8*)(xt + ((size_t)n * 64 + l31) * 16 + h * 8);
  const bf16x8 x1 = *(const bf16x8*)(xt + ((size_t)n * 64 + 32 + l31) * 16 + h * 8);

  #pragma unroll 2
  for (int tt = 0; tt < 16; ++tt) {
    const int t = th * 16 + tt;
    const bf16x8 wfr =
        *(const bf16x8*)(wb + ((size_t)n * JO_ + t * 32 + l31) * 16 + h * 8);
    f32x16 p0 = __builtin_amdgcn_mfma_f32_32x32x16_bf16(wfr, x0, zero16, 0, 0, 0);
    f32x16 p1 = __builtin_amdgcn_mfma_f32_32x32x16_bf16(wfr, x1, zero16, 0, 0, 0);
    float s0 = 0.f, s1 = 0.f;
    #pragma unroll
    for (int g = 0; g < 4; ++g) {
      const int vbase = (((t * 4 + g) * 2 + h) * 64) * 4;  // u16 units, b=0
      const ushort4 va = *(const ushort4*)(v4 + vbase + l31 * 4);
      const ushort4 vb = *(const ushort4*)(v4 + vbase + (32 + l31) * 4);
      s0 += p0[g * 4 + 0] * bf2f(va.x) + p0[g * 4 + 1] * bf2f(va.y)
          + p0[g * 4 + 2] * bf2f(va.z) + p0[g * 4 + 3] * bf2f(va.w);
      s1 += p1[g * 4 + 0] * bf2f(vb.x) + p1[g * 4 + 1] * bf2f(vb.y)
          + p1[g * 4 + 2] * bf2f(vb.z) + p1[g * 4 + 3] * bf2f(vb.w);
    }
    s0 += __shfl_xor(s0, 32, 64);   // combine h-halves (same col b)
    s1 += __shfl_xor(s1, 32, 64);
    // lane = h*32+l31 writes b=lane's logit: h=0 lanes own b=l31 (s0),
    // h=1 lanes own b=32+l31 (s1). Bank = (lane+t)%32 -> 2-way, free.
    lgs[nl][lane][t] = h ? s1 : s0;
  }
  __syncthreads();

  if (tid < 128) {
    const int nl2 = tid >> 6, b = tid & 63;
    const int n2 = blockIdx.x * 2 + nl2;
    float lv[32];
    float mx = -1e30f;
    #pragma unroll
    for (int t = 0; t < 32; ++t) {
      lv[t] = lgs[nl2][b][t];
      mx = fmaxf(mx, lv[t]);
    }
    float sm = 0.f;
    #pragma unroll
    for (int t = 0; t < 32; ++t) { lv[t] = __expf(lv[t] - mx); sm += lv[t]; }
    const float inv = 1.f / sm;
    #pragma unroll
    for (int t = 0; t < 32; ++t) {
      ct[((size_t)t * N_ + n2) * 64 + b] = f2bf(lv[t] * inv);
    }
  }
}

// ---------------------------------------------------------------------------
extern "C" void kernel_launch(void* const* d_in, const int* in_sizes, int n_in,
                              void* d_out, int out_size, void* d_ws, size_t ws_size,
                              hipStream_t stream) {
  const float* x = (const float*)d_in[0];
  const float* w = (const float*)d_in[1];
  float* out = (float*)d_out;
  char* ws = (char*)d_ws;
  // layout: wb 64MB | ct 8MB | xt 4MB | s_sum 256K | v0 256K | v4 128K
  u16*   wb    = (u16*)ws;
  u16*   ct    = (u16*)(ws + (size_t)64 * 1024 * 1024);
  u16*   xt    = (u16*)(ws + (size_t)72 * 1024 * 1024);
  float* s_sum = (float*)(ws + (size_t)76 * 1024 * 1024);
  float* v0    = (float*)(ws + (size_t)76 * 1024 * 1024 + 262144);
  u16*   v4    = (u16*)(ws + (size_t)76 * 1024 * 1024 + 2 * 262144);

  const size_t s_bytes = (size_t)JO_ * B_ * sizeof(float);
  dim3 sfg(32, 32), sfb(256);
  dim3 ag(1024), ab(256);
  dim3 rg(1024), rb(64);

  xconv_kernel<<<dim3(512), dim3(256), 0, stream>>>(x, xt);
  wconv_kernel<<<dim3(8192), dim3(256), 0, stream>>>(w, wb);
  // iter 0: uniform c folded as scale=1/32 in r_kernel
  hipMemsetAsync(s_sum, 0, s_bytes, stream);
  sf_kernel<<<sfg, sfb, 0, stream>>>(xt, wb, ct, s_sum, 1);
  r_kernel<<<rg, rb, 0, stream>>>(s_sum, v0, v0, v4, out, 0, 0.03125f);
  // iter 1
  a_kernel<<<ag, ab, 0, stream>>>(xt, wb, v4, ct);
  hipMemsetAsync(s_sum, 0, s_bytes, stream);
  sf_kernel<<<sfg, sfb, 0, stream>>>(xt, wb, ct, s_sum, 0);
  r_kernel<<<rg, rb, 0, stream>>>(s_sum, v0, v0, v4, out, 1, 1.0f);
  // iter 2 (logits = pred . (v0+v1) via v4)
  a_kernel<<<ag, ab, 0, stream>>>(xt, wb, v4, ct);
  hipMemsetAsync(s_sum, 0, s_bytes, stream);
  sf_kernel<<<sfg, sfb, 0, stream>>>(xt, wb, ct, s_sum, 0);
  r_kernel<<<rg, rb, 0, stream>>>(s_sum, v0, v0, v4, out, 2, 1.0f);
}

// Round 3
// 331.028 us; speedup vs baseline: 1.3574x; 1.0035x over previous
//
#include <hip/hip_runtime.h>
#include <hip/hip_bf16.h>

#define B_ 64
#define N_ 2048
#define I_ 16
#define J_ 32
#define O_ 32
#define JO_ 1024
#define SPLITS 32

typedef __attribute__((ext_vector_type(8))) short bf16x8;
typedef __attribute__((ext_vector_type(16))) float f32x16;
typedef unsigned short u16;
typedef unsigned int u32;

__device__ __forceinline__ float bf2f(u16 u) {
  union { u32 i; float f; } c; c.i = ((u32)u) << 16; return c.f;
}
__device__ __forceinline__ u16 f2bf(float f) {
  union { float f; u32 i; } c; c.f = f;
  u32 r = (c.i + 0x7fffu + ((c.i >> 16) & 1u)) >> 16;
  return (u16)r;
}
// one-instruction pack of 2 f32 -> 2 bf16 (RNE), replaces ~9-op manual path
__device__ __forceinline__ u32 pack2_pk(float lo, float hi) {
  u32 r;
  asm("v_cvt_pk_bf16_f32 %0, %1, %2" : "=v"(r) : "v"(lo), "v"(hi));
  return r;
}
// scale packed bf16 pair by cv: unpack (shift / mask-as-hi-bits), mul, cvt_pk
__device__ __forceinline__ u32 scale2_pk(u32 p, float cv) {
  union { u32 i; float f; } lo, hi;
  lo.i = p << 16; hi.i = p & 0xffff0000u;
  return pack2_pk(lo.f * cv, hi.f * cv);
}

// ---------------------------------------------------------------------------
// xconv: x f32 [b][n][i] -> xt bf16 [n][b][i]
// ---------------------------------------------------------------------------
__global__ __launch_bounds__(256) void xconv_kernel(
    const float* __restrict__ xf, u16* __restrict__ xt)
{
  const int idx = blockIdx.x * 256 + threadIdx.x;   // = b*2048 + n
  const int b = idx >> 11, n = idx & 2047;
  const float4* sp = (const float4*)(xf + (size_t)idx * 16);
  float4 f0 = sp[0], f1 = sp[1], f2 = sp[2], f3 = sp[3];
  uint4 d0, d1;
  d0.x = pack2_pk(f0.x, f0.y); d0.y = pack2_pk(f0.z, f0.w);
  d0.z = pack2_pk(f1.x, f1.y); d0.w = pack2_pk(f1.z, f1.w);
  d1.x = pack2_pk(f2.x, f2.y); d1.y = pack2_pk(f2.z, f2.w);
  d1.z = pack2_pk(f3.x, f3.y); d1.w = pack2_pk(f3.z, f3.w);
  uint4* dp = (uint4*)(xt + ((size_t)n * 64 + b) * 16);
  dp[0] = d0; dp[1] = d1;
}

// ---------------------------------------------------------------------------
// WSF kernel: fused wconv + sf iter-0 (uniform c).
// Reads w f32 once, converts to bf16 in-register, writes wb for later passes,
// and accumulates the iter-0 s partial in the same trip (saves a 64MB wb
// re-read + a full pass's launch/latency).
// grid (32 j, 32 split), block 256. Partials to s_part[split] (no atomics).
// ---------------------------------------------------------------------------
#define SF_NPW 16

__global__ __launch_bounds__(256, 4) void wsf_kernel(
    const float* __restrict__ wf, u16* __restrict__ wb,
    const u16* __restrict__ xt, float* __restrict__ s_part)
{
  __shared__ float red[4][2048];   // 32 KB
  const int tid = threadIdx.x;
  const int wave = tid >> 6, lane = tid & 63;
  const int l31 = lane & 31, h = lane >> 5;
  const int j = blockIdx.x, split = blockIdx.y;
  const int n0 = (split * 4 + wave) * SF_NPW;
  f32x16 acc0 = {0.f, 0.f, 0.f, 0.f, 0.f, 0.f, 0.f, 0.f,
                 0.f, 0.f, 0.f, 0.f, 0.f, 0.f, 0.f, 0.f};
  f32x16 acc1 = acc0;

  #pragma unroll 4
  for (int i = 0; i < SF_NPW; ++i) {
    const int n = n0 + i;
    const size_t row = (size_t)n * JO_ + j * 32 + l31;
    // read w f32 directly: lane covers its 8-i half of the row
    const float* wsrc = wf + row * 16 + h * 8;
    const float4 f0 = *(const float4*)(wsrc);
    const float4 f1 = *(const float4*)(wsrc + 4);
    union { uint4 u4; bf16x8 bv; } wd;
    wd.u4.x = pack2_pk(f0.x, f0.y); wd.u4.y = pack2_pk(f0.z, f0.w);
    wd.u4.z = pack2_pk(f1.x, f1.y); wd.u4.w = pack2_pk(f1.z, f1.w);
    *(uint4*)(wb + row * 16 + h * 8) = wd.u4;   // persist for a/sf passes
    const bf16x8 x0 = *(const bf16x8*)(xt + ((size_t)n * 64 + l31) * 16 + h * 8);
    const bf16x8 x1 = *(const bf16x8*)(xt + ((size_t)n * 64 + 32 + l31) * 16 + h * 8);
    acc0 = __builtin_amdgcn_mfma_f32_32x32x16_bf16(wd.bv, x0, acc0, 0, 0, 0);
    acc1 = __builtin_amdgcn_mfma_f32_32x32x16_bf16(wd.bv, x1, acc1, 0, 0, 0);
  }
  #pragma unroll
  for (int r = 0; r < 16; ++r) {
    const int o = (r & 3) + 8 * (r >> 2) + 4 * h;
    red[wave][o * 64 + l31] = acc0[r];
    red[wave][o * 64 + 32 + l31] = acc1[r];
  }
  __syncthreads();
  float* dst = s_part + (size_t)split * (JO_ * B_) + (size_t)j * 32 * 64;
  #pragma unroll
  for (int k = 0; k < 8; ++k) {
    const int idx = tid + 256 * k;
    dst[idx] = red[0][idx] + red[1][idx] + red[2][idx] + red[3][idx];
  }
}

// ---------------------------------------------------------------------------
// SF kernel (iters 1,2): s_part[split][jo][b] = sum_n c[b,n,j]*pred[b,n,jo]
// c-scaling now via v_cvt_pk_bf16_f32 (5 ops/u32 vs 12) — was VALU-bound.
// Partials instead of atomicAdd (r_kernel reduces them).
// ---------------------------------------------------------------------------
__global__ __launch_bounds__(256, 4) void sf_kernel(
    const u16* __restrict__ xt, const u16* __restrict__ wb,
    const u16* __restrict__ ct, float* __restrict__ s_part)
{
  __shared__ float red[4][2048];   // 32 KB
  const int tid = threadIdx.x;
  const int wave = tid >> 6, lane = tid & 63;
  const int l31 = lane & 31, h = lane >> 5;
  const int j = blockIdx.x, split = blockIdx.y;
  const int n0 = (split * 4 + wave) * SF_NPW;
  f32x16 acc0 = {0.f, 0.f, 0.f, 0.f, 0.f, 0.f, 0.f, 0.f,
                 0.f, 0.f, 0.f, 0.f, 0.f, 0.f, 0.f, 0.f};
  f32x16 acc1 = acc0;

  #pragma unroll 4
  for (int i = 0; i < SF_NPW; ++i) {
    const int n = n0 + i;
    bf16x8 wfr = *(const bf16x8*)(wb + ((size_t)n * JO_ + j * 32 + l31) * 16 + h * 8);
    union { bf16x8 v; u32 u[4]; } a, b2;
    a.v = *(const bf16x8*)(xt + ((size_t)n * 64 + l31) * 16 + h * 8);
    b2.v = *(const bf16x8*)(xt + ((size_t)n * 64 + 32 + l31) * 16 + h * 8);
    const float cv0 = bf2f(ct[((size_t)j * N_ + n) * 64 + l31]);
    const float cv1 = bf2f(ct[((size_t)j * N_ + n) * 64 + 32 + l31]);
    a.u[0] = scale2_pk(a.u[0], cv0); a.u[1] = scale2_pk(a.u[1], cv0);
    a.u[2] = scale2_pk(a.u[2], cv0); a.u[3] = scale2_pk(a.u[3], cv0);
    b2.u[0] = scale2_pk(b2.u[0], cv1); b2.u[1] = scale2_pk(b2.u[1], cv1);
    b2.u[2] = scale2_pk(b2.u[2], cv1); b2.u[3] = scale2_pk(b2.u[3], cv1);
    acc0 = __builtin_amdgcn_mfma_f32_32x32x16_bf16(wfr, a.v, acc0, 0, 0, 0);
    acc1 = __builtin_amdgcn_mfma_f32_32x32x16_bf16(wfr, b2.v, acc1, 0, 0, 0);
  }
  #pragma unroll
  for (int r = 0; r < 16; ++r) {
    const int o = (r & 3) + 8 * (r >> 2) + 4 * h;
    red[wave][o * 64 + l31] = acc0[r];
    red[wave][o * 64 + 32 + l31] = acc1[r];
  }
  __syncthreads();
  float* dst = s_part + (size_t)split * (JO_ * B_) + (size_t)j * 32 * 64;
  #pragma unroll
  for (int k = 0; k < 8; ++k) {
    const int idx = tid + 256 * k;
    dst[idx] = red[0][idx] + red[1][idx] + red[2][idx] + red[3][idx];
  }
}

// ---------------------------------------------------------------------------
// R kernel: reduce 32 partials + squash over o.
// mode 0: write v f32 + v4=f2bf(v); 1: v4=f2bf(v+vprev); 2: write out.
// v4 layout [j][g][h][b][4o] so a_kernel's dot loads are contiguous.
// grid 1024 (= 64 b x 16 jgroups), block 64 (2 j x 32 o).
// ---------------------------------------------------------------------------
__global__ __launch_bounds__(64) void r_kernel(
    const float* __restrict__ s_part, float* __restrict__ v,
    const float* __restrict__ vprev, u16* __restrict__ v4,
    float* __restrict__ out, int mode, float scale)
{
  const int tid = threadIdx.x;
  const int jj = tid >> 5, o = tid & 31;
  const int b = blockIdx.x >> 4, jg = blockIdx.x & 15;
  const int j = jg * 2 + jj;
  const size_t off_jo = (size_t)(j * 32 + o) * 64 + b;
  float s = 0.f;
  #pragma unroll
  for (int k = 0; k < SPLITS; ++k) s += s_part[(size_t)k * (JO_ * B_) + off_jo];
  s *= scale;
  float sq = s * s;
  #pragma unroll
  for (int m = 16; m >= 1; m >>= 1) sq += __shfl_xor(sq, m, 64);
  const float sc = sq / (1.f + sq) * rsqrtf(sq + 1e-8f);
  const float vv = sc * s;
  const size_t off = (size_t)b * JO_ + j * 32 + o;
  const int g = o >> 3, hh = (o >> 2) & 1, rr = o & 3;
  const size_t v4off = ((((size_t)j * 4 + g) * 2 + hh) * 64 + b) * 4 + rr;
  if (mode == 0) { v[off] = vv; v4[v4off] = f2bf(vv); }
  else if (mode == 1) { v4[v4off] = f2bf(vv + vprev[off]); }
  else { out[off] = vv; }
}

// ---------------------------------------------------------------------------
// A kernel: ONE n per block, 4 waves x 8 j-tiles each -> grid 2048 blocks
// (= 8/CU potential; __launch_bounds__(256,6) caps VGPR at ~84, 75% occ).
// Logits to LDS; softmax by wave 0 (one b per lane); coalesced ct store
// phase (all 256 threads, consecutive b within a t-row).
// ---------------------------------------------------------------------------
__global__ __launch_bounds__(256, 6) void a_kernel(
    const u16* __restrict__ xt, const u16* __restrict__ wb,
    const u16* __restrict__ v4, u16* __restrict__ ct)
{
  __shared__ float lgs[64][33];   // [b][j], pad 33 -> conflict-free
  const int tid = threadIdx.x;
  const int wave = tid >> 6, lane = tid & 63;
  const int l31 = lane & 31, h = lane >> 5;
  const int n = blockIdx.x;
  const f32x16 zero16 = {0.f, 0.f, 0.f, 0.f, 0.f, 0.f, 0.f, 0.f,
                         0.f, 0.f, 0.f, 0.f, 0.f, 0.f, 0.f, 0.f};

  // B-frags: x cols b = l31 and 32+l31
  const bf16x8 x0 = *(const bf16x8*)(xt + ((size_t)n * 64 + l31) * 16 + h * 8);
  const bf16x8 x1 = *(const bf16x8*)(xt + ((size_t)n * 64 + 32 + l31) * 16 + h * 8);

  #pragma unroll 2
  for (int tt = 0; tt < 8; ++tt) {
    const int t = wave * 8 + tt;
    const bf16x8 wfr =
        *(const bf16x8*)(wb + ((size_t)n * JO_ + t * 32 + l31) * 16 + h * 8);
    f32x16 p0 = __builtin_amdgcn_mfma_f32_32x32x16_bf16(wfr, x0, zero16, 0, 0, 0);
    f32x16 p1 = __builtin_amdgcn_mfma_f32_32x32x16_bf16(wfr, x1, zero16, 0, 0, 0);
    float s0 = 0.f, s1 = 0.f;
    #pragma unroll
    for (int g = 0; g < 4; ++g) {
      const int vbase = (((t * 4 + g) * 2 + h) * 64) * 4;  // u16 units, b=0
      const ushort4 va = *(const ushort4*)(v4 + vbase + l31 * 4);
      const ushort4 vb = *(const ushort4*)(v4 + vbase + (32 + l31) * 4);
      s0 += p0[g * 4 + 0] * bf2f(va.x) + p0[g * 4 + 1] * bf2f(va.y)
          + p0[g * 4 + 2] * bf2f(va.z) + p0[g * 4 + 3] * bf2f(va.w);
      s1 += p1[g * 4 + 0] * bf2f(vb.x) + p1[g * 4 + 1] * bf2f(vb.y)
          + p1[g * 4 + 2] * bf2f(vb.z) + p1[g * 4 + 3] * bf2f(vb.w);
    }
    s0 += __shfl_xor(s0, 32, 64);   // combine h-halves (same col b)
    s1 += __shfl_xor(s1, 32, 64);
    // h=0 lanes own b=l31 (s0), h=1 lanes own b=32+l31 (s1)
    lgs[lane][t] = h ? s1 : s0;
  }
  __syncthreads();

  if (tid < 64) {                    // softmax: one (n,b) per lane, wave 0
    const int b = tid;
    float lv[32];
    float mx = -1e30f;
    #pragma unroll
    for (int t = 0; t < 32; ++t) { lv[t] = lgs[b][t]; mx = fmaxf(mx, lv[t]); }
    float sm = 0.f;
    #pragma unroll
    for (int t = 0; t < 32; ++t) { lv[t] = __expf(lv[t] - mx); sm += lv[t]; }
    const float inv = 1.f / sm;
    #pragma unroll
    for (int t = 0; t < 32; ++t) lgs[b][t] = lv[t] * inv;  // write back c
  }
  __syncthreads();

  // coalesced ct store: consecutive tid -> consecutive b within a t-row
  #pragma unroll
  for (int k = 0; k < 8; ++k) {
    const int idx = k * 256 + tid;
    const int t = idx >> 6, b = idx & 63;
    ct[((size_t)t * N_ + n) * 64 + b] = f2bf(lgs[b][t]);
  }
}

// ---------------------------------------------------------------------------
extern "C" void kernel_launch(void* const* d_in, const int* in_sizes, int n_in,
                              void* d_out, int out_size, void* d_ws, size_t ws_size,
                              hipStream_t stream) {
  const float* x = (const float*)d_in[0];
  const float* w = (const float*)d_in[1];
  float* out = (float*)d_out;
  char* ws = (char*)d_ws;
  // layout: wb 64MB | ct 8MB | xt 4MB | s_part 8MB | v0 256K | v4 128K
  u16*   wb     = (u16*)ws;
  u16*   ct     = (u16*)(ws + (size_t)64 * 1024 * 1024);
  u16*   xt     = (u16*)(ws + (size_t)72 * 1024 * 1024);
  float* s_part = (float*)(ws + (size_t)76 * 1024 * 1024);
  float* v0     = (float*)(ws + (size_t)84 * 1024 * 1024);
  u16*   v4     = (u16*)(ws + (size_t)84 * 1024 * 1024 + 262144);

  dim3 sfg(32, SPLITS), sfb(256);
  dim3 ag(2048), ab(256);
  dim3 rg(1024), rb(64);

  xconv_kernel<<<dim3(512), dim3(256), 0, stream>>>(x, xt);
  // iter 0: fused wconv + uniform-c accumulate (c folded as 1/32 in r)
  wsf_kernel<<<sfg, sfb, 0, stream>>>(w, wb, xt, s_part);
  r_kernel<<<rg, rb, 0, stream>>>(s_part, v0, v0, v4, out, 0, 0.03125f);
  // iter 1
  a_kernel<<<ag, ab, 0, stream>>>(xt, wb, v4, ct);
  sf_kernel<<<sfg, sfb, 0, stream>>>(xt, wb, ct, s_part);
  r_kernel<<<rg, rb, 0, stream>>>(s_part, v0, v0, v4, out, 1, 1.0f);
  // iter 2 (logits = pred . (v0+v1) via v4)
  a_kernel<<<ag, ab, 0, stream>>>(xt, wb, v4, ct);
  sf_kernel<<<sfg, sfb, 0, stream>>>(xt, wb, ct, s_part);
  r_kernel<<<rg, rb, 0, stream>>>(s_part, v0, v0, v4, out, 2, 1.0f);
}